// Round 23
// baseline (121.535 us; speedup 1.0000x reference)
//
#include <hip/hip_runtime.h>
#include <hip/hip_bf16.h>

// GCNConv: one-pass fixed-capacity binning (32 tgts/bucket, CAP slots each) ->
// fused per-bucket {LDS counting sort + node-pair quarter-lane gather +
// epilogue}. No fp32 global atomics anywhere.
// agg[c] = dinv[c] * ( xs[c] + sum_{e: col[e]==c} xs[row[e]] ),
//   xs[i] = (x@W)[i] * dinv[i],  dinv[i] = rsqrt(1 + indeg(i))
// out = dropout(tanh(agg + b)), JAX partitionable-threefry key (0,42), p_keep=0.9:
//   bits[p] = o0^o1 of threefry((0,42), 0, p); u = bitcast(bits>>9|0x3f800000)-1; keep = u<0.9.
//
// R8: __shfl only in uniform regions (predicated regions contain loads only).
// R22: deg handoff -> sagg 54.5us; p1+xw ~61us remain (p1 reads tgt twice).
// R23: buckets = 32 tgts (NB=3125) so sagg reads ONLY its own region (sort
//   read halved, half-filter gone); p1 single-pass with register-cached edges
//   (second 12.8MB ei read deleted). pk format unchanged: src | (t&63)<<17 —
//   xw local row = (pk>>17)&63, sagg node idx = (pk>>17)&31.
//
// ws (~20.4 MB): xsh bf16[NN*64] | packed u32[NB*CAP] | gcur i32[NB] |
//                gspill i32[1] | spill_pk u32[SPILLCAP] | spill_bk u32[SPILLCAP] |
//                deg_g i32[NN]

#define NN 100000
#define NE 1600000
#define NB 3125             // NN/32 exactly; bucket = tgt>>5
#define P1B 256
#define P1T 1024
#define CHUNK 6250          // P1B * CHUNK == NE
#define NSLOT 7             // ceil(CHUNK/P1T) register slots per thread
#define CAP 576             // per-bucket region (mean 512, +2.8 sigma)
#define SPILLCAP 2048
#define HCAP 1536           // per-bucket LDS sort capacity

// ---------------- Threefry2x32 (JAX-exact) ----------------
__device__ __forceinline__ unsigned rotl32(unsigned x, int r) {
    return (x << r) | (x >> (32 - r));
}

__device__ __forceinline__ void threefry2x32(unsigned k0, unsigned k1,
                                             unsigned x0, unsigned x1,
                                             unsigned& o0, unsigned& o1) {
    const unsigned ks0 = k0, ks1 = k1, ks2 = k0 ^ k1 ^ 0x1BD11BDAu;
    x0 += ks0; x1 += ks1;
    x0 += x1; x1 = rotl32(x1, 13); x1 ^= x0;
    x0 += x1; x1 = rotl32(x1, 15); x1 ^= x0;
    x0 += x1; x1 = rotl32(x1, 26); x1 ^= x0;
    x0 += x1; x1 = rotl32(x1, 6);  x1 ^= x0;
    x0 += ks1; x1 += ks2 + 1u;
    x0 += x1; x1 = rotl32(x1, 17); x1 ^= x0;
    x0 += x1; x1 = rotl32(x1, 29); x1 ^= x0;
    x0 += x1; x1 = rotl32(x1, 16); x1 ^= x0;
    x0 += x1; x1 = rotl32(x1, 24); x1 ^= x0;
    x0 += ks2; x1 += ks0 + 2u;
    x0 += x1; x1 = rotl32(x1, 13); x1 ^= x0;
    x0 += x1; x1 = rotl32(x1, 15); x1 ^= x0;
    x0 += x1; x1 = rotl32(x1, 26); x1 ^= x0;
    x0 += x1; x1 = rotl32(x1, 6);  x1 ^= x0;
    x0 += ks0; x1 += ks1 + 3u;
    x0 += x1; x1 = rotl32(x1, 17); x1 ^= x0;
    x0 += x1; x1 = rotl32(x1, 29); x1 ^= x0;
    x0 += x1; x1 = rotl32(x1, 16); x1 ^= x0;
    x0 += x1; x1 = rotl32(x1, 24); x1 ^= x0;
    x0 += ks1; x1 += ks2 + 4u;
    x0 += x1; x1 = rotl32(x1, 13); x1 ^= x0;
    x0 += x1; x1 = rotl32(x1, 15); x1 ^= x0;
    x0 += x1; x1 = rotl32(x1, 26); x1 ^= x0;
    x0 += x1; x1 = rotl32(x1, 6);  x1 ^= x0;
    x0 += ks2; x1 += ks0 + 5u;
    o0 = x0; o1 = x1;
}

// Per-node epilogue: quarter-reduce, redistribute, tanh + threefry dropout.
// Contains shfls — call ONLY under wave-uniform control flow.
__device__ __forceinline__ void sagg_finish(float4 a0, float4 a1, int lane,
                                            int c, float dv, float bv,
                                            float* __restrict__ out) {
    float ax = a0.x + a1.x, ay = a0.y + a1.y;
    float az = a0.z + a1.z, aw = a0.w + a1.w;
    ax += __shfl_xor(ax, 16); ax += __shfl_xor(ax, 32);
    ay += __shfl_xor(ay, 16); ay += __shfl_xor(ay, 32);
    az += __shfl_xor(az, 16); az += __shfl_xor(az, 32);
    aw += __shfl_xor(aw, 16); aw += __shfl_xor(aw, 32);
    const float sx = __shfl(ax, lane >> 2);
    const float sy = __shfl(ay, lane >> 2);
    const float sz = __shfl(az, lane >> 2);
    const float sw = __shfl(aw, lane >> 2);
    const float ab = (lane & 1) ? sy : sx;
    const float cd = (lane & 1) ? sw : sz;
    const float a = (lane & 2) ? cd : ab;
    const int p = c * 64 + lane;
    unsigned o0, o1;
    threefry2x32(0u, 42u, 0u, (unsigned)p, o0, o1);
    const unsigned bits = o0 ^ o1;
    const float u = __uint_as_float((bits >> 9) | 0x3f800000u) - 1.0f;
    const float h = tanhf(dv * a + bv);
    out[p] = (u < 0.9f) ? h / 0.9f : 0.0f;
}

#define UNPK4(v, A)                                                    \
    A.x += __uint_as_float((v).x << 16);                               \
    A.y += __uint_as_float((v).x & 0xffff0000u);                       \
    A.z += __uint_as_float((v).y << 16);                               \
    A.w += __uint_as_float((v).y & 0xffff0000u);

// ---------------- Kernels ----------------
// One-pass binning: edges register-cached during LDS hist, one global reserve
// atomic per (block,bucket), grouped writes into fixed regions, spill overflow.
__global__ __launch_bounds__(P1T) void k_p1(const int* __restrict__ ei,
                                            int* __restrict__ gcur,
                                            unsigned* __restrict__ packed,
                                            unsigned* __restrict__ spill_pk,
                                            unsigned* __restrict__ spill_bk,
                                            int* __restrict__ gspill) {
    __shared__ int hb[NB];   // 12.5 KB
    __shared__ int lc[NB];   // 12.5 KB
    const int tid = threadIdx.x;
    for (int i = tid; i < NB; i += P1T) { hb[i] = 0; lc[i] = 0; }
    __syncthreads();
    const int base = blockIdx.x * CHUNK;
    unsigned tc[NSLOT], sc[NSLOT];   // register-cached edges (static idx)
#pragma unroll
    for (int k = 0; k < NSLOT; ++k) {
        const int i = tid + k * P1T;
        tc[k] = 0xFFFFFFFFu;
        sc[k] = 0u;
        if (i < CHUNK) {
            const unsigned t = (unsigned)ei[NE + base + i];
            tc[k] = t;
            sc[k] = (unsigned)ei[base + i];
            if (t < NN) atomicAdd(&hb[t >> 5], 1);
        }
    }
    __syncthreads();
    for (int i = tid; i < NB; i += P1T) {
        const int h = hb[i];
        hb[i] = h ? atomicAdd(&gcur[i], h) : 0;  // reserve (may exceed CAP)
        lc[i] = 0;
    }
    __syncthreads();
#pragma unroll
    for (int k = 0; k < NSLOT; ++k) {
        const unsigned t = tc[k];
        if (t >= NN) continue;
        const int bk = (int)(t >> 5);
        const unsigned pk = sc[k] | ((t & 63u) << 17);
        const int pos = hb[bk] + atomicAdd(&lc[bk], 1);
        if (pos < CAP) {
            packed[(size_t)bk * CAP + pos] = pk;
        } else {  // rare overflow: graceful spill
            const int sp = atomicAdd(gspill, 1);
            if (sp < SPILLCAP) { spill_pk[sp] = pk; spill_bk[sp] = (unsigned)bk; }
        }
    }
}

// x@W, lane=row: one 64-thread wave per 64 rows (= buckets 2b, 2b+1). x staged
// in padded LDS [64][65]; W via wave-uniform scalar loads (s_load + SGPR FMA).
// deg hist from the two regions (+spill), persisted to deg_g for k_sagg.
__global__ __launch_bounds__(64) void k_xw(const float* __restrict__ x,
                                           const float* __restrict__ W,
                                           const unsigned* __restrict__ packed,
                                           const int* __restrict__ gcur,
                                           const unsigned* __restrict__ spill_pk,
                                           const unsigned* __restrict__ spill_bk,
                                           const int* __restrict__ gspill,
                                           int* __restrict__ deg_g,
                                           __hip_bfloat16* __restrict__ xsh) {
    __shared__ float xl[64 * 65];   // 16.64 KB (reused as out-bounce)
    __shared__ int hist[64];
    const int lane = threadIdx.x;   // block == 1 wave; lane == local row
    const int b = blockIdx.x;       // covers rows [64b, 64b+64) = buckets 2b, 2b+1
    const int row0 = b * 64;
    const int nrow = (NN - row0) < 64 ? (NN - row0) : 64;
    {   // stage x rows, coalesced float4; LDS row stride 65 floats
        const float4* __restrict__ xg = (const float4*)(x + (size_t)row0 * 64);
        const int nf4 = nrow * 16;
        for (int i = lane; i < nf4; i += 64) {
            const int r = i >> 4, q = i & 15;
            *(float4*)&xl[r * 65 + 4 * q] = xg[i];
        }
    }
    hist[lane] = 0;
    __syncthreads();
    {   // degree hist over buckets 2b and 2b+1; local row = (pk>>17)&63
#pragma unroll 1
        for (int h2 = 0; h2 < 2; ++h2) {
            const int bk = 2 * b + h2;
            if (bk >= NB) break;
            int cnt = gcur[bk];
            cnt = (cnt < 0) ? 0 : (cnt > CAP ? CAP : cnt);
            const unsigned* __restrict__ seg = packed + (size_t)bk * CAP;
            for (int i = lane; i < cnt; i += 64)
                atomicAdd(&hist[(seg[i] >> 17) & 63u], 1);
        }
        int ns = *gspill;
        ns = (ns < 0) ? 0 : (ns > SPILLCAP ? SPILLCAP : ns);
        for (int i = lane; i < ns; i += 64)
            if ((int)(spill_bk[i] >> 1) == b)
                atomicAdd(&hist[(spill_pk[i] >> 17) & 63u], 1);
    }
    __syncthreads();
    const int myrow = row0 + lane;
    if (myrow < NN) deg_g[myrow] = hist[lane];  // persist for k_sagg
    const float dv = rsqrtf(1.0f + (float)hist[lane]);
    float acc[64];
#pragma unroll
    for (int d = 0; d < 64; ++d) acc[d] = 0.0f;
#pragma unroll 1
    for (int k = 0; k < 64; ++k) {
        const float xv = xl[lane * 65 + k];  // per-lane, (lane+k)%32 banks
#pragma unroll
        for (int d = 0; d < 64; ++d)         // W[k*64+d] is wave-uniform ->
            acc[d] = fmaf(xv, W[k * 64 + d], acc[d]);  // s_load + SGPR FMA
    }
    __syncthreads();  // xl reuse as bounce buffer
    unsigned* __restrict__ ol = (unsigned*)xl;  // [64][33] packed bf16 pairs
#pragma unroll
    for (int q = 0; q < 32; ++q) {
        const __hip_bfloat16 b0 = __float2bfloat16(acc[2 * q] * dv);
        const __hip_bfloat16 b1 = __float2bfloat16(acc[2 * q + 1] * dv);
        const unsigned w = ((unsigned)*(const unsigned short*)&b1 << 16) |
                           *(const unsigned short*)&b0;
        ol[lane * 33 + q] = w;  // bank (lane+q)%32: 2-way, free
    }
    __syncthreads();
    unsigned* __restrict__ og = (unsigned*)(xsh + (size_t)row0 * 64);
    const int nw = nrow * 32;
    for (int i = lane; i < nw; i += 64) {  // coalesced global store
        const int r = i >> 5, q = i & 31;
        og[i] = ol[r * 33 + q];
    }
}

// Fused per-bucket sort + NODE-PAIR aggregate + epilogue. One block per
// 32-node bucket (3125 blocks); reads ONLY its own region (no half filter).
// Degrees from deg_g (coalesced). Gather: 2 nodes/iter, 4 chains, 4
// predicated uint2 loads in flight; quarter-lanes (q=lane>>4, sl=lane&15).
__global__ __launch_bounds__(256) void k_sagg(const unsigned* __restrict__ packed,
                                              const int* __restrict__ gcur,
                                              const unsigned* __restrict__ spill_pk,
                                              const unsigned* __restrict__ spill_bk,
                                              const int* __restrict__ gspill,
                                              const int* __restrict__ deg_g,
                                              const __hip_bfloat16* __restrict__ xsh,
                                              const float* __restrict__ bias,
                                              float* __restrict__ out) {
    __shared__ unsigned sorted[HCAP];  // 6 KB
    __shared__ int hist[32];
    __shared__ int pref[32];
    __shared__ int cur[32];
    __shared__ float sdinv[32];
    const int tid = threadIdx.x;
    const int b = blockIdx.x;          // bucket; nodes [32b, 32b+32)
    int seg = gcur[b];
    seg = (seg < 0) ? 0 : (seg > CAP ? CAP : seg);
    const unsigned* __restrict__ region = packed + (size_t)b * CAP;
    int ns = *gspill;
    ns = (ns < 0) ? 0 : (ns > SPILLCAP ? SPILLCAP : ns);
    if (tid < 32) {  // degrees from k_xw (includes spill) — no region scan
        const int c = b * 32 + tid;
        hist[tid] = (c < NN) ? deg_g[c] : 0;
    }
    __syncthreads();
    if (tid == 0) {
        int run = 0;
        for (int t = 0; t < 32; ++t) { pref[t] = run; run += hist[t]; }
    }
    __syncthreads();
    const int hcnt = pref[31] + hist[31];
    const bool oversize = (hcnt > HCAP);
    if (tid < 32) {
        cur[tid] = pref[tid];
        sdinv[tid] = rsqrtf(1.0f + (float)hist[tid]);
    }
    __syncthreads();
    if (!oversize) {
        for (int i = tid; i < seg; i += 256) {
            const unsigned pk = region[i];
            const int pos = atomicAdd(&cur[(pk >> 17) & 31u], 1);
            if (pos < HCAP) sorted[pos] = pk & 0x1FFFFu;
        }
        for (int i = tid; i < ns; i += 256) {  // spill: ~0-20 entries
            if ((int)spill_bk[i] == b) {
                const unsigned pk = spill_pk[i];
                const int pos = atomicAdd(&cur[(pk >> 17) & 31u], 1);
                if (pos < HCAP) sorted[pos] = pk & 0x1FFFFu;
            }
        }
    }
    __syncthreads();

    const int wid = tid >> 6, lane = tid & 63;
    const int q = lane >> 4, sl = lane & 15;   // quarter, dim-quad
    const uint2* __restrict__ xs4 = (const uint2*)xsh;  // 4 bf16 per elem
    const float bv = bias[lane];
#pragma unroll 1
    for (int t = 0; t < 8; t += 2) {
        const int nlA = wid * 8 + t, nlB = nlA + 1;   // node pair
        const int cA = b * 32 + nlA;
        const int cB = cA + 1;
        if (cA >= NN) break;               // wave-uniform (defensive)
        const bool hasB = (cB < NN);       // wave-uniform
        const int offA = pref[nlA], offB = pref[nlB];
        int degA = hist[nlA];
        degA = (degA < 0) ? 0 : (degA > hcnt ? hcnt : degA);
        int degB = hasB ? hist[nlB] : 0;
        degB = (degB < 0) ? 0 : (degB > hcnt ? hcnt : degB);
        float4 a0A = {0.f,0.f,0.f,0.f}, a1A = {0.f,0.f,0.f,0.f};
        float4 a0B = {0.f,0.f,0.f,0.f}, a1B = {0.f,0.f,0.f,0.f};
        if (q == 0) {  // self-loop terms
            const uint2 vA = xs4[(size_t)cA * 16 + sl];
            UNPK4(vA, a0A)
            if (hasB) {
                const uint2 vB = xs4[(size_t)cB * 16 + sl];
                UNPK4(vB, a0B)
            }
        }
        if (!oversize) {
            const int dmax = (degA > degB) ? degA : degB;  // wave-uniform
            for (int j = 0; j < dmax; j += 8) {
                const int e0 = j + q, e1 = j + 4 + q;
                uint2 v0A = {0u,0u}, v1A = {0u,0u}, v0B = {0u,0u}, v1B = {0u,0u};
                if (e0 < degA) v0A = xs4[(size_t)sorted[offA + e0] * 16 + sl];
                if (e1 < degA) v1A = xs4[(size_t)sorted[offA + e1] * 16 + sl];
                if (e0 < degB) v0B = xs4[(size_t)sorted[offB + e0] * 16 + sl];
                if (e1 < degB) v1B = xs4[(size_t)sorted[offB + e1] * 16 + sl];
                UNPK4(v0A, a0A)
                UNPK4(v1A, a1A)
                UNPK4(v0B, a0B)
                UNPK4(v1B, a1B)
            }
        } else {  // scan-mode fallback: region + spill, node-tagged (rare)
            if (q == 0) {
                const unsigned tlA = (unsigned)(nlA);
                const unsigned tlB = tlA + 1u;
                for (int i = 0; i < seg; ++i) {
                    const unsigned pk = region[i];
                    const unsigned tl = (pk >> 17) & 31u;
                    if (tl == tlA) {
                        const uint2 v = xs4[(size_t)(pk & 0x1FFFFu) * 16 + sl];
                        UNPK4(v, a0A)
                    }
                    if (hasB && tl == tlB) {
                        const uint2 v = xs4[(size_t)(pk & 0x1FFFFu) * 16 + sl];
                        UNPK4(v, a0B)
                    }
                }
                for (int i = 0; i < ns; ++i) {
                    if ((int)spill_bk[i] == b) {
                        const unsigned pk = spill_pk[i];
                        const unsigned tl = (pk >> 17) & 31u;
                        if (tl == tlA) {
                            const uint2 v = xs4[(size_t)(pk & 0x1FFFFu) * 16 + sl];
                            UNPK4(v, a0A)
                        }
                        if (hasB && tl == tlB) {
                            const uint2 v = xs4[(size_t)(pk & 0x1FFFFu) * 16 + sl];
                            UNPK4(v, a0B)
                        }
                    }
                }
            }
        }
        sagg_finish(a0A, a1A, lane, cA, sdinv[nlA], bv, out);
        if (hasB) sagg_finish(a0B, a1B, lane, cB, sdinv[nlB], bv, out);
    }
}

extern "C" void kernel_launch(void* const* d_in, const int* in_sizes, int n_in,
                              void* d_out, int out_size, void* d_ws, size_t ws_size,
                              hipStream_t stream) {
    const float* x  = (const float*)d_in[0];
    const float* W  = (const float*)d_in[1];
    const float* b  = (const float*)d_in[2];
    const int*   ei = (const int*)d_in[3];
    float* out = (float*)d_out;

    __hip_bfloat16* xsh = (__hip_bfloat16*)d_ws;              // bf16[NN*64]
    unsigned* packed = (unsigned*)(xsh + (size_t)NN * 64);    // u32[NB*CAP]
    int* gcur = (int*)(packed + (size_t)NB * CAP);            // i32[NB]
    int* gspill = gcur + NB;                                  // i32[1]
    unsigned* spill_pk = (unsigned*)(gspill + 1);             // u32[SPILLCAP]
    unsigned* spill_bk = spill_pk + SPILLCAP;                 // u32[SPILLCAP]
    int* deg_g = (int*)(spill_bk + SPILLCAP);                 // i32[NN]

    hipMemsetAsync(gcur, 0, (NB + 1) * sizeof(int), stream);
    k_p1<<<P1B, P1T, 0, stream>>>(ei, gcur, packed, spill_pk, spill_bk, gspill);
    k_xw<<<(NN + 63) / 64, 64, 0, stream>>>(x, W, packed, gcur, spill_pk, spill_bk, gspill, deg_g, xsh);
    k_sagg<<<NB, 256, 0, stream>>>(packed, gcur, spill_pk, spill_bk, gspill, deg_g, xsh, b, out);
}